// Round 1
// 249.354 us; speedup vs baseline: 1.0011x; 1.0011x over previous
//
#include <hip/hip_runtime.h>
#include <stdint.h>

#define B_ 8
#define S_ 1024
#define D_ 1024
#define H_ 16
#define DK_ 64
#define DV_ 64

typedef __attribute__((ext_vector_type(8))) short short8;
typedef __attribute__((ext_vector_type(4))) float f32x4;

__device__ __forceinline__ unsigned short f2bf(float f) {
  union { float f; unsigned u; } v; v.f = f;
  return (unsigned short)((v.u + 0x7fffu + ((v.u >> 16) & 1u)) >> 16);
}
__device__ __forceinline__ unsigned short f2bf_trunc(float f) {
  union { float f; unsigned u; } v; v.f = f;
  return (unsigned short)(v.u >> 16);
}

// async global->LDS, 16B per lane; LDS dest = wave-uniform base + lane*16
__device__ __forceinline__ void ld_lds16(const unsigned short* g, unsigned short* l) {
  __builtin_amdgcn_global_load_lds((const __attribute__((address_space(1))) void*)g,
                                   (__attribute__((address_space(3))) void*)l, 16, 0, 0);
}

// -------- fused prep: x fp32->bf16 (z>=4) + 4 weight transposes (z<4) --------
// z 0..3: transpose W[z] (K,N) fp32 -> (N,K) bf16, 64x64 tile per block.
// z 4..35: cvt slice; block handles 1024 contiguous elems (256 thr x 4).
__global__ __launch_bounds__(256) void prep_kernel(const float* __restrict__ x,
                                                   unsigned short* __restrict__ xb,
                                                   const float* __restrict__ W0,
                                                   const float* __restrict__ W1,
                                                   const float* __restrict__ W2,
                                                   const float* __restrict__ W3,
                                                   unsigned short* __restrict__ T0,
                                                   unsigned short* __restrict__ T1,
                                                   unsigned short* __restrict__ T2,
                                                   unsigned short* __restrict__ T3) {
  const int z = blockIdx.z;
  if (z >= 4) {
    size_t blk = (size_t)(z - 4) * 256 + blockIdx.y * 16 + blockIdx.x;
    size_t i = (blk * 256 + threadIdx.x) * 4;
    float4 v = *(const float4*)(x + i);
    ushort4 o;
    o.x = f2bf(v.x); o.y = f2bf(v.y); o.z = f2bf(v.z); o.w = f2bf(v.w);
    *(ushort4*)(xb + i) = o;
    return;
  }
  __shared__ __align__(16) unsigned short tl[64][65];
  const float* W; unsigned short* Wt;
  switch (z) {
    case 0: W = W0; Wt = T0; break;
    case 1: W = W1; Wt = T1; break;
    case 2: W = W2; Wt = T2; break;
    default: W = W3; Wt = T3; break;
  }
  const int xx = threadIdx.x & 63;
  const int y4 = threadIdx.x >> 6;
  const int bn = blockIdx.x * 64;   // N base
  const int bk = blockIdx.y * 64;   // K base
  #pragma unroll
  for (int r = y4; r < 64; r += 4)
    tl[r][xx] = f2bf(W[(size_t)(bk + r) * 1024 + bn + xx]);
  __syncthreads();
  #pragma unroll
  for (int r = y4; r < 64; r += 4)
    Wt[(size_t)(bn + r) * 1024 + bk + xx] = tl[xx][r];
}

// ---------------- BK=64 staging helper: XOR-swizzled tiles ----------------
__device__ __forceinline__ void stage_tile64(const unsigned short* __restrict__ G,
                                             unsigned short* __restrict__ Ls,
                                             int t, int wslot, size_t rowstride, int k0) {
  #pragma unroll
  for (int i = 0; i < 4; i++) {
    int s = i * 256 + t;
    int r = s >> 3, c = (s & 7) ^ (r & 7);
    ld_lds16(G + (size_t)r * rowstride + k0 + c * 8, &Ls[(i * 256 + wslot) * 8]);
  }
}

// ------------- fused QKV GEMM (BK=64): A (8192x1024), Bt (3072x1024) -------
// blockIdx.x 0..7  -> q (B,H,S,DK) bf16, scaled by 0.125*log2(e)
// blockIdx.x 8..15 -> k (B,H,S,DK) bf16
// blockIdx.x 16..23-> v (B,H,DV,S) bf16, transposed operands, MASK FOLDED IN:
//                     V'[d][s] = (V[d][s]+bias)*mask[s]
__global__ __launch_bounds__(256) void gemm_qkv(const unsigned short* __restrict__ A,
                                                const unsigned short* __restrict__ Bt,
                                                const float* __restrict__ bq,
                                                const float* __restrict__ bk,
                                                const float* __restrict__ bv,
                                                const int* __restrict__ masks,
                                                unsigned short* __restrict__ q,
                                                unsigned short* __restrict__ kk,
                                                unsigned short* __restrict__ vT) {
  const int K = 1024;
  __shared__ __align__(16) unsigned short As[128 * 64];
  __shared__ __align__(16) unsigned short Bs[128 * 64];
  const int t = threadIdx.x;
  const int wave = t >> 6, lane = t & 63;
  const int l15 = lane & 15, quad = lane >> 4;
  const int l7 = l15 & 7;
  const int bm = blockIdx.y * 128, bn = blockIdx.x * 128;
  const int wm = (wave & 1) * 64, wn = (wave >> 1) * 64;
  const bool vsec = (blockIdx.x >= 16);
  const int wslot = (t & ~63);

  f32x4 acc[4][4] = {};
  const unsigned short* Ag = A + (size_t)bm * K;
  const unsigned short* Bg = Bt + (size_t)bn * K;

  for (int k0 = 0; k0 < K; k0 += 64) {
    __syncthreads();
    stage_tile64(Ag, As, t, wslot, K, k0);
    stage_tile64(Bg, Bs, t, wslot, K, k0);
    __syncthreads();
    #pragma unroll
    for (int kf = 0; kf < 2; kf++) {
      short8 af[4], bf[4];
      #pragma unroll
      for (int mi = 0; mi < 4; mi++)
        af[mi] = *(const short8*)&As[(wm + mi * 16 + l15) * 64 + (((kf << 2) | quad) ^ l7) * 8];
      #pragma unroll
      for (int ni = 0; ni < 4; ni++)
        bf[ni] = *(const short8*)&Bs[(wn + ni * 16 + l15) * 64 + (((kf << 2) | quad) ^ l7) * 8];
      if (vsec) {
        #pragma unroll
        for (int mi = 0; mi < 4; mi++)
          #pragma unroll
          for (int ni = 0; ni < 4; ni++)
            acc[mi][ni] = __builtin_amdgcn_mfma_f32_16x16x32_bf16(bf[ni], af[mi], acc[mi][ni], 0, 0, 0);
      } else {
        #pragma unroll
        for (int mi = 0; mi < 4; mi++)
          #pragma unroll
          for (int ni = 0; ni < 4; ni++)
            acc[mi][ni] = __builtin_amdgcn_mfma_f32_16x16x32_bf16(af[mi], bf[ni], acc[mi][ni], 0, 0, 0);
      }
    }
  }

  if (!vsec) {
    int sec = blockIdx.x >> 3;   // 0 -> q, 1 -> k
    const float* bsel = (sec == 0) ? bq : bk;
    unsigned short* dst = (sec == 0) ? q : kk;
    float scale = (sec == 0) ? 0.180336880f : 1.0f;  // 0.125*log2(e) folded into q
    #pragma unroll
    for (int ni = 0; ni < 4; ni++) {
      int c = ((bn & 1023) + wn + ni * 16 + l15);
      float bvv = bsel[c];
      int hh = c >> 6, d = c & 63;
      #pragma unroll
      for (int mi = 0; mi < 4; mi++) {
        int row0 = bm + wm + mi * 16 + quad * 4;
        #pragma unroll
        for (int r = 0; r < 4; r++) {
          int row = row0 + r;
          int b = row >> 10, s = row & 1023;
          dst[(((size_t)(b * H_ + hh)) * S_ + s) * DK_ + d] = f2bf((acc[mi][ni][r] + bvv) * scale);
        }
      }
    }
  } else {
    // transposed accum: lane l15 -> row (s), quad*4+r -> col (d); mask folded
    #pragma unroll
    for (int ni = 0; ni < 4; ni++) {
      int cbase = (bn & 1023) + wn + ni * 16;
      #pragma unroll
      for (int mi = 0; mi < 4; mi++) {
        int row = bm + wm + mi * 16 + l15;
        int b = row >> 10, s = row & 1023;
        float mf = (masks[b * S_ + s] != 0) ? 1.0f : 0.0f;
        #pragma unroll
        for (int r = 0; r < 4; r++) {
          int c = cbase + quad * 4 + r;
          int hh = c >> 6, d = c & 63;
          vT[(((size_t)(b * H_ + hh)) * DV_ + d) * S_ + s] = f2bf((acc[mi][ni][r] + bv[c]) * mf);
        }
      }
    }
  }
}

// ------- out GEMM (BK=64): A (8192x1024) bf16, Bt (1024x1024) -> fp32 ------
__global__ __launch_bounds__(256) void gemm_out(const unsigned short* __restrict__ A,
                                                const unsigned short* __restrict__ Bt,
                                                const float* __restrict__ bias,
                                                float* __restrict__ Cout) {
  const int K = 1024, N = 1024;
  __shared__ __align__(16) unsigned short As[128 * 64];
  __shared__ __align__(16) unsigned short Bs[128 * 64];
  const int t = threadIdx.x;
  const int wave = t >> 6, lane = t & 63;
  const int l15 = lane & 15, quad = lane >> 4;
  const int l7 = l15 & 7;
  const int bm = blockIdx.y * 128, bn = blockIdx.x * 128;
  const int wm = (wave & 1) * 64, wn = (wave >> 1) * 64;
  const int wslot = (t & ~63);

  f32x4 acc[4][4] = {};
  const unsigned short* Ag = A + (size_t)bm * K;
  const unsigned short* Bg = Bt + (size_t)bn * K;

  for (int k0 = 0; k0 < K; k0 += 64) {
    __syncthreads();
    stage_tile64(Ag, As, t, wslot, K, k0);
    stage_tile64(Bg, Bs, t, wslot, K, k0);
    __syncthreads();
    #pragma unroll
    for (int kf = 0; kf < 2; kf++) {
      short8 af[4], bf[4];
      #pragma unroll
      for (int mi = 0; mi < 4; mi++)
        af[mi] = *(const short8*)&As[(wm + mi * 16 + l15) * 64 + (((kf << 2) | quad) ^ l7) * 8];
      #pragma unroll
      for (int ni = 0; ni < 4; ni++)
        bf[ni] = *(const short8*)&Bs[(wn + ni * 16 + l15) * 64 + (((kf << 2) | quad) ^ l7) * 8];
      #pragma unroll
      for (int mi = 0; mi < 4; mi++)
        #pragma unroll
        for (int ni = 0; ni < 4; ni++)
          acc[mi][ni] = __builtin_amdgcn_mfma_f32_16x16x32_bf16(af[mi], bf[ni], acc[mi][ni], 0, 0, 0);
    }
  }

  #pragma unroll
  for (int ni = 0; ni < 4; ni++) {
    int col = bn + wn + ni * 16 + l15;
    float bvv = bias[col];
    #pragma unroll
    for (int mi = 0; mi < 4; mi++) {
      int row0 = bm + wm + mi * 16 + quad * 4;
      #pragma unroll
      for (int r = 0; r < 4; r++)
        Cout[(size_t)(row0 + r) * N + col] = acc[mi][ni][r] + bvv;
    }
  }
}

// ------------------------- flash attention v2 -------------------------
// grid: (B*H, S/128) -- bh on x so all 8 qt-blocks of a bh share an XCD
// (linear%8 = bh%8 since gridDim.x=128 is a multiple of 8) -> K/V L2 reuse.
// QK^T computed transposed (swapped operands): P written as b64; mask+l-sum
// offloaded to MFMA via pre-masked V' and a mask row (l in acc col 0).
// K/V staging is T14 async-split: issue global->reg prefetch for tile kt+1
// right after the top barrier, ds_write regs->LDS at the top of the next
// iteration. HBM/L2 latency hides under the ~1000cy compute phase instead
// of being drained serially by global_load_lds + vmcnt(0) + barrier.
#define PLD 72
__global__ __launch_bounds__(256) void attn_kernel(const unsigned short* __restrict__ Q,
                                                   const unsigned short* __restrict__ Kb,
                                                   const unsigned short* __restrict__ Vt,
                                                   const int* __restrict__ masks,
                                                   unsigned short* __restrict__ O) {
  __shared__ __align__(16) unsigned short QP[128 * PLD];  // Q staged (stride 64), then P (stride 72)
  __shared__ __align__(16) unsigned short Ks[64 * 64];
  __shared__ __align__(16) unsigned short Vs[80 * 64];    // rows 0..63 V', row 64 mask
  const int t = threadIdx.x;
  const int wave = t >> 6, lane = t & 63;
  const int l15 = lane & 15, quad = lane >> 4;
  const int l7 = l15 & 7;
  const int bh = blockIdx.x;       // 0..127  (XCD-locality key)
  const int qt = blockIdx.y;       // 0..7
  const int b = bh >> 4, h = bh & 15;

  const unsigned short* Qg = Q + ((size_t)bh * S_ + qt * 128) * DK_;
  const unsigned short* Kg = Kb + (size_t)bh * S_ * DK_;
  const unsigned short* Vg = Vt + (size_t)bh * DV_ * S_;
  const int wslot = (t & ~63);

  // Q -> LDS (async), overlapped with the tile-0 K/V reg prefetch below
  #pragma unroll
  for (int i = 0; i < 4; i++) {
    int p = i * 256 + t;
    ld_lds16(Qg + (size_t)p * 8, &QP[(i * 256 + wslot) * 8]);
  }

  // prefetch pointers: slot p writes LDS slot p (16B), source pre-swizzled
  const int p0 = t, p1 = 256 + t;
  const int rk0 = p0 >> 3, ck0 = (p0 & 7) ^ (rk0 & 7);
  const int rk1 = p1 >> 3, ck1 = (p1 & 7) ^ (rk1 & 7);
  const unsigned short* kp0 = Kg + (size_t)rk0 * DK_ + ck0 * 8;
  const unsigned short* kp1 = Kg + (size_t)rk1 * DK_ + ck1 * 8;
  const unsigned short* vp0 = Vg + (size_t)rk0 * S_ + ck0 * 8;
  const unsigned short* vp1 = Vg + (size_t)rk1 * S_ + ck1 * 8;

  // mask values for the whole block, preloaded: iter kt's row is written by
  // wave (kt&3) from mv[kt>>2]
  int mv[4];
  #pragma unroll
  for (int j = 0; j < 4; j++)
    mv[j] = masks[b * S_ + (j * 4 + wave) * 64 + lane];

  // tile 0 K/V into regs (in flight alongside Q's global_load_lds)
  short8 kr0 = *(const short8*)kp0;
  short8 kr1 = *(const short8*)kp1;
  short8 vr0 = *(const short8*)vp0;
  short8 vr1 = *(const short8*)vp1;

  __syncthreads();   // Q visible

  // Q fragments (B-operand): rows = q, plain stride 64
  short8 aq[2][2];
  #pragma unroll
  for (int mb = 0; mb < 2; mb++)
    #pragma unroll
    for (int kf = 0; kf < 2; kf++)
      aq[mb][kf] = *(const short8*)&QP[(wave * 32 + mb * 16 + l15) * 64 + kf * 32 + quad * 8];

  f32x4 o_acc[2][5] = {};   // [mb][n]; n==4 is the l column (col 0 valid)

  for (int kt = 0; kt < 16; kt++) {
    // write the staged regs (tile kt) to LDS
    *(short8*)&Ks[p0 * 8] = kr0;
    *(short8*)&Ks[p1 * 8] = kr1;
    *(short8*)&Vs[p0 * 8] = vr0;
    *(short8*)&Vs[p1 * 8] = vr1;
    if (wave == (kt & 3))
      Vs[64 * 64 + lane] = (mv[kt >> 2] != 0) ? (unsigned short)0x3F80 : (unsigned short)0;
    __syncthreads();

    // issue tile kt+1 prefetch; completes under the compute below
    if (kt < 15) {
      kp0 += 64 * DK_; kp1 += 64 * DK_; vp0 += 64; vp1 += 64;
      kr0 = *(const short8*)kp0;
      kr1 = *(const short8*)kp1;
      vr0 = *(const short8*)vp0;
      vr1 = *(const short8*)vp1;
    }

    // S^T = K·Q^T : lane l15 = q, quad*4+r = key (within 16-tile)
    f32x4 sc[2][4];
    #pragma unroll
    for (int n = 0; n < 4; n++) {
      short8 bk0 = *(const short8*)&Ks[(n * 16 + l15) * 64 + (quad ^ l7) * 8];
      short8 bk1 = *(const short8*)&Ks[(n * 16 + l15) * 64 + ((4 + quad) ^ l7) * 8];
      #pragma unroll
      for (int mb = 0; mb < 2; mb++) {
        f32x4 c = {};
        c = __builtin_amdgcn_mfma_f32_16x16x32_bf16(bk0, aq[mb][0], c, 0, 0, 0);
        c = __builtin_amdgcn_mfma_f32_16x16x32_bf16(bk1, aq[mb][1], c, 0, 0, 0);
        sc[mb][n] = c;
      }
    }
    // exp2 + packed b64 P write: P[q][key]
    #pragma unroll
    for (int mb = 0; mb < 2; mb++)
      #pragma unroll
      for (int n = 0; n < 4; n++) {
        ushort4 pk;
        pk.x = f2bf_trunc(exp2f(sc[mb][n][0]));
        pk.y = f2bf_trunc(exp2f(sc[mb][n][1]));
        pk.z = f2bf_trunc(exp2f(sc[mb][n][2]));
        pk.w = f2bf_trunc(exp2f(sc[mb][n][3]));
        *(ushort4*)&QP[(wave * 32 + mb * 16 + l15) * PLD + n * 16 + quad * 4] = pk;
      }
    // PV (+l): O[q][d] += P[q][key]·V'[key][d]; n=4 reads mask row -> l in col 0
    #pragma unroll
    for (int kf = 0; kf < 2; kf++) {
      short8 ap[2];
      #pragma unroll
      for (int mb = 0; mb < 2; mb++)
        ap[mb] = *(const short8*)&QP[(wave * 32 + mb * 16 + l15) * PLD + kf * 32 + quad * 8];
      #pragma unroll
      for (int n = 0; n < 5; n++) {
        short8 bv = *(const short8*)&Vs[(n * 16 + l15) * 64 + ((kf * 4 + quad) ^ l7) * 8];
        #pragma unroll
        for (int mb = 0; mb < 2; mb++)
          o_acc[mb][n] = __builtin_amdgcn_mfma_f32_16x16x32_bf16(ap[mb], bv, o_acc[mb][n], 0, 0, 0);
      }
    }
    __syncthreads();  // all waves done reading Ks/Vs before next ds_write
  }

  // epilogue: l lives in o_acc[mb][4][r] at l15==0 -> broadcast within quad
  #pragma unroll
  for (int mb = 0; mb < 2; mb++)
    #pragma unroll
    for (int r = 0; r < 4; r++) {
      float l = __shfl(o_acc[mb][4][r], lane & 48, 64);
      float inv = 1.0f / l;
      int qrow = qt * 128 + wave * 32 + mb * 16 + quad * 4 + r;
      #pragma unroll
      for (int n = 0; n < 4; n++) {
        int col = h * 64 + n * 16 + l15;
        O[((size_t)b * S_ + qrow) * D_ + col] = f2bf(o_acc[mb][n][r] * inv);
      }
    }
}

extern "C" void kernel_launch(void* const* d_in, const int* in_sizes, int n_in,
                              void* d_out, int out_size, void* d_ws, size_t ws_size,
                              hipStream_t stream) {
  (void)in_sizes; (void)n_in; (void)out_size; (void)ws_size;
  const float* x  = (const float*)d_in[0];
  const int* masks = (const int*)d_in[1];
  const float* Wq = (const float*)d_in[2];
  const float* bq = (const float*)d_in[3];
  const float* Wk = (const float*)d_in[4];
  const float* bk = (const float*)d_in[5];
  const float* Wv = (const float*)d_in[6];
  const float* bv = (const float*)d_in[7];
  const float* Wo = (const float*)d_in[8];
  const float* bo = (const float*)d_in[9];

  char* p = (char*)d_ws;
  unsigned short* xb    = (unsigned short*)p; p += (size_t)8192 * 1024 * 2;
  unsigned short* WqkvT = (unsigned short*)p; p += (size_t)3072 * 1024 * 2;
  unsigned short* WoT   = (unsigned short*)p; p += (size_t)1024 * 1024 * 2;
  unsigned short* q     = (unsigned short*)p; p += (size_t)8192 * 1024 * 2;
  unsigned short* kk    = (unsigned short*)p; p += (size_t)8192 * 1024 * 2;
  unsigned short* vT    = (unsigned short*)p; p += (size_t)8192 * 1024 * 2;
  unsigned short* at    = (unsigned short*)p; p += (size_t)8192 * 1024 * 2;

  prep_kernel<<<dim3(16, 16, 36), 256, 0, stream>>>(
      x, xb, Wq, Wk, Wv, Wo,
      WqkvT, WqkvT + (size_t)1024 * 1024, WqkvT + (size_t)2048 * 1024, WoT);
  gemm_qkv<<<dim3(24, 64), 256, 0, stream>>>(xb, WqkvT, bq, bk, bv, masks, q, kk, vT);
  attn_kernel<<<dim3(128, 8), 256, 0, stream>>>(q, kk, vT, masks, at);
  gemm_out<<<dim3(8, 64), 256, 0, stream>>>(at, WoT, bo, (float*)d_out);
}

// Round 2
// 241.408 us; speedup vs baseline: 1.0341x; 1.0329x over previous
//
#include <hip/hip_runtime.h>
#include <stdint.h>

#define B_ 8
#define S_ 1024
#define D_ 1024
#define H_ 16
#define DK_ 64
#define DV_ 64

typedef __attribute__((ext_vector_type(8))) short short8;
typedef __attribute__((ext_vector_type(4))) float f32x4;

__device__ __forceinline__ unsigned short f2bf(float f) {
  union { float f; unsigned u; } v; v.f = f;
  return (unsigned short)((v.u + 0x7fffu + ((v.u >> 16) & 1u)) >> 16);
}
__device__ __forceinline__ unsigned short f2bf_trunc(float f) {
  union { float f; unsigned u; } v; v.f = f;
  return (unsigned short)(v.u >> 16);
}

// async global->LDS, 16B per lane; LDS dest = wave-uniform base + lane*16
__device__ __forceinline__ void ld_lds16(const unsigned short* g, unsigned short* l) {
  __builtin_amdgcn_global_load_lds((const __attribute__((address_space(1))) void*)g,
                                   (__attribute__((address_space(3))) void*)l, 16, 0, 0);
}

// -------- fused prep: x fp32->bf16 (z>=4) + 4 weight transposes (z<4) --------
__global__ __launch_bounds__(256) void prep_kernel(const float* __restrict__ x,
                                                   unsigned short* __restrict__ xb,
                                                   const float* __restrict__ W0,
                                                   const float* __restrict__ W1,
                                                   const float* __restrict__ W2,
                                                   const float* __restrict__ W3,
                                                   unsigned short* __restrict__ T0,
                                                   unsigned short* __restrict__ T1,
                                                   unsigned short* __restrict__ T2,
                                                   unsigned short* __restrict__ T3) {
  const int z = blockIdx.z;
  if (z >= 4) {
    size_t blk = (size_t)(z - 4) * 256 + blockIdx.y * 16 + blockIdx.x;
    size_t i = (blk * 256 + threadIdx.x) * 4;
    float4 v = *(const float4*)(x + i);
    ushort4 o;
    o.x = f2bf(v.x); o.y = f2bf(v.y); o.z = f2bf(v.z); o.w = f2bf(v.w);
    *(ushort4*)(xb + i) = o;
    return;
  }
  __shared__ __align__(16) unsigned short tl[64][65];
  const float* W; unsigned short* Wt;
  switch (z) {
    case 0: W = W0; Wt = T0; break;
    case 1: W = W1; Wt = T1; break;
    case 2: W = W2; Wt = T2; break;
    default: W = W3; Wt = T3; break;
  }
  const int xx = threadIdx.x & 63;
  const int y4 = threadIdx.x >> 6;
  const int bn = blockIdx.x * 64;   // N base
  const int bk = blockIdx.y * 64;   // K base
  #pragma unroll
  for (int r = y4; r < 64; r += 4)
    tl[r][xx] = f2bf(W[(size_t)(bk + r) * 1024 + bn + xx]);
  __syncthreads();
  #pragma unroll
  for (int r = y4; r < 64; r += 4)
    Wt[(size_t)(bn + r) * 1024 + bk + xx] = tl[xx][r];
}

// ---------------- BK=64 staging helper: XOR-swizzled tiles ----------------
__device__ __forceinline__ void stage_tile64(const unsigned short* __restrict__ G,
                                             unsigned short* __restrict__ Ls,
                                             int t, int wslot, size_t rowstride, int k0) {
  #pragma unroll
  for (int i = 0; i < 4; i++) {
    int s = i * 256 + t;
    int r = s >> 3, c = (s & 7) ^ (r & 7);
    ld_lds16(G + (size_t)r * rowstride + k0 + c * 8, &Ls[(i * 256 + wslot) * 8]);
  }
}

// ------------- fused QKV GEMM (BK=64): A (8192x1024), Bt (3072x1024) -------
__global__ __launch_bounds__(256) void gemm_qkv(const unsigned short* __restrict__ A,
                                                const unsigned short* __restrict__ Bt,
                                                const float* __restrict__ bq,
                                                const float* __restrict__ bk,
                                                const float* __restrict__ bv,
                                                const int* __restrict__ masks,
                                                unsigned short* __restrict__ q,
                                                unsigned short* __restrict__ kk,
                                                unsigned short* __restrict__ vT) {
  const int K = 1024;
  __shared__ __align__(16) unsigned short As[128 * 64];
  __shared__ __align__(16) unsigned short Bs[128 * 64];
  const int t = threadIdx.x;
  const int wave = t >> 6, lane = t & 63;
  const int l15 = lane & 15, quad = lane >> 4;
  const int l7 = l15 & 7;
  const int bm = blockIdx.y * 128, bn = blockIdx.x * 128;
  const int wm = (wave & 1) * 64, wn = (wave >> 1) * 64;
  const bool vsec = (blockIdx.x >= 16);
  const int wslot = (t & ~63);

  f32x4 acc[4][4] = {};
  const unsigned short* Ag = A + (size_t)bm * K;
  const unsigned short* Bg = Bt + (size_t)bn * K;

  for (int k0 = 0; k0 < K; k0 += 64) {
    __syncthreads();
    stage_tile64(Ag, As, t, wslot, K, k0);
    stage_tile64(Bg, Bs, t, wslot, K, k0);
    __syncthreads();
    #pragma unroll
    for (int kf = 0; kf < 2; kf++) {
      short8 af[4], bf[4];
      #pragma unroll
      for (int mi = 0; mi < 4; mi++)
        af[mi] = *(const short8*)&As[(wm + mi * 16 + l15) * 64 + (((kf << 2) | quad) ^ l7) * 8];
      #pragma unroll
      for (int ni = 0; ni < 4; ni++)
        bf[ni] = *(const short8*)&Bs[(wn + ni * 16 + l15) * 64 + (((kf << 2) | quad) ^ l7) * 8];
      if (vsec) {
        #pragma unroll
        for (int mi = 0; mi < 4; mi++)
          #pragma unroll
          for (int ni = 0; ni < 4; ni++)
            acc[mi][ni] = __builtin_amdgcn_mfma_f32_16x16x32_bf16(bf[ni], af[mi], acc[mi][ni], 0, 0, 0);
      } else {
        #pragma unroll
        for (int mi = 0; mi < 4; mi++)
          #pragma unroll
          for (int ni = 0; ni < 4; ni++)
            acc[mi][ni] = __builtin_amdgcn_mfma_f32_16x16x32_bf16(af[mi], bf[ni], acc[mi][ni], 0, 0, 0);
      }
    }
  }

  if (!vsec) {
    int sec = blockIdx.x >> 3;   // 0 -> q, 1 -> k
    const float* bsel = (sec == 0) ? bq : bk;
    unsigned short* dst = (sec == 0) ? q : kk;
    float scale = (sec == 0) ? 0.180336880f : 1.0f;  // 0.125*log2(e) folded into q
    #pragma unroll
    for (int ni = 0; ni < 4; ni++) {
      int c = ((bn & 1023) + wn + ni * 16 + l15);
      float bvv = bsel[c];
      int hh = c >> 6, d = c & 63;
      #pragma unroll
      for (int mi = 0; mi < 4; mi++) {
        int row0 = bm + wm + mi * 16 + quad * 4;
        #pragma unroll
        for (int r = 0; r < 4; r++) {
          int row = row0 + r;
          int b = row >> 10, s = row & 1023;
          dst[(((size_t)(b * H_ + hh)) * S_ + s) * DK_ + d] = f2bf((acc[mi][ni][r] + bvv) * scale);
        }
      }
    }
  } else {
    // transposed accum: lane l15 -> row (s), quad*4+r -> col (d); mask folded
    #pragma unroll
    for (int ni = 0; ni < 4; ni++) {
      int cbase = (bn & 1023) + wn + ni * 16;
      #pragma unroll
      for (int mi = 0; mi < 4; mi++) {
        int row = bm + wm + mi * 16 + l15;
        int b = row >> 10, s = row & 1023;
        float mf = (masks[b * S_ + s] != 0) ? 1.0f : 0.0f;
        #pragma unroll
        for (int r = 0; r < 4; r++) {
          int c = cbase + quad * 4 + r;
          int hh = c >> 6, d = c & 63;
          vT[(((size_t)(b * H_ + hh)) * DV_ + d) * S_ + s] = f2bf((acc[mi][ni][r] + bv[c]) * mf);
        }
      }
    }
  }
}

// ------- out GEMM (BK=64): A (8192x1024) bf16, Bt (1024x1024) -> fp32 ------
__global__ __launch_bounds__(256) void gemm_out(const unsigned short* __restrict__ A,
                                                const unsigned short* __restrict__ Bt,
                                                const float* __restrict__ bias,
                                                float* __restrict__ Cout) {
  const int K = 1024, N = 1024;
  __shared__ __align__(16) unsigned short As[128 * 64];
  __shared__ __align__(16) unsigned short Bs[128 * 64];
  const int t = threadIdx.x;
  const int wave = t >> 6, lane = t & 63;
  const int l15 = lane & 15, quad = lane >> 4;
  const int l7 = l15 & 7;
  const int bm = blockIdx.y * 128, bn = blockIdx.x * 128;
  const int wm = (wave & 1) * 64, wn = (wave >> 1) * 64;
  const int wslot = (t & ~63);

  f32x4 acc[4][4] = {};
  const unsigned short* Ag = A + (size_t)bm * K;
  const unsigned short* Bg = Bt + (size_t)bn * K;

  for (int k0 = 0; k0 < K; k0 += 64) {
    __syncthreads();
    stage_tile64(Ag, As, t, wslot, K, k0);
    stage_tile64(Bg, Bs, t, wslot, K, k0);
    __syncthreads();
    #pragma unroll
    for (int kf = 0; kf < 2; kf++) {
      short8 af[4], bf[4];
      #pragma unroll
      for (int mi = 0; mi < 4; mi++)
        af[mi] = *(const short8*)&As[(wm + mi * 16 + l15) * 64 + (((kf << 2) | quad) ^ l7) * 8];
      #pragma unroll
      for (int ni = 0; ni < 4; ni++)
        bf[ni] = *(const short8*)&Bs[(wn + ni * 16 + l15) * 64 + (((kf << 2) | quad) ^ l7) * 8];
      #pragma unroll
      for (int mi = 0; mi < 4; mi++)
        #pragma unroll
        for (int ni = 0; ni < 4; ni++)
          acc[mi][ni] = __builtin_amdgcn_mfma_f32_16x16x32_bf16(af[mi], bf[ni], acc[mi][ni], 0, 0, 0);
    }
  }

  #pragma unroll
  for (int ni = 0; ni < 4; ni++) {
    int col = bn + wn + ni * 16 + l15;
    float bvv = bias[col];
    #pragma unroll
    for (int mi = 0; mi < 4; mi++) {
      int row0 = bm + wm + mi * 16 + quad * 4;
      #pragma unroll
      for (int r = 0; r < 4; r++)
        Cout[(size_t)(row0 + r) * N + col] = acc[mi][ni][r] + bvv;
    }
  }
}

// ------------------------- flash attention v3 -------------------------
// grid: (B*H, S/128) -- bh on x for XCD-local K/V L2 reuse.
// Staging: global_load_lds (kept -- r1 showed reg-staging is net-negative
// here), but now DOUBLE-BUFFERED with the T3-minimal schedule:
//   prologue: stage tile0; barrier
//   iter kt : issue stage(kt+1 -> buf^1); compute(buf); ONE barrier
// The vmcnt(0) drain at the barrier now waits on loads issued ~1000cy
// earlier (before the MFMA/exp phase) -> staging latency hidden.
// Q fragments are loaded straight global->reg (no Q staging pass).
// exp2 via __builtin_amdgcn_exp2f (1 v_exp_f32, no OCML expansion).
#define PLD 72
#define VROWS 65   // per-buffer V rows: 64 V' + 1 mask row
__global__ __launch_bounds__(256) void attn_kernel(const unsigned short* __restrict__ Q,
                                                   const unsigned short* __restrict__ Kb,
                                                   const unsigned short* __restrict__ Vt,
                                                   const int* __restrict__ masks,
                                                   unsigned short* __restrict__ O) {
  __shared__ __align__(16) unsigned short Pl[128 * PLD];            // P tiles (stride 72)
  __shared__ __align__(16) unsigned short Ks[2 * 64 * 64];          // K dbuf
  __shared__ __align__(16) unsigned short Vs[(2 * VROWS + 15) * 64];// V' dbuf + mask rows
                                                                    // (+15 rows so the n==4
                                                                    // garbage reads of buf1
                                                                    // stay in-bounds)
  const int t = threadIdx.x;
  const int wave = t >> 6, lane = t & 63;
  const int l15 = lane & 15, quad = lane >> 4;
  const int l7 = l15 & 7;
  const int bh = blockIdx.x;       // 0..127  (XCD-locality key)
  const int qt = blockIdx.y;       // 0..7
  const int b = bh >> 4, h = bh & 15;

  const unsigned short* Qg = Q + ((size_t)bh * S_ + qt * 128) * DK_;
  const unsigned short* Kg = Kb + (size_t)bh * S_ * DK_;
  const unsigned short* Vg = Vt + (size_t)bh * DV_ * S_;
  const int wslot = (t & ~63);

  // mask values for the whole block, preloaded: tile T's row is written by
  // wave (T&3) from mv[T>>2]
  int mv[4];
  #pragma unroll
  for (int j = 0; j < 4; j++)
    mv[j] = masks[b * S_ + (j * 4 + wave) * 64 + lane];

  // Q fragments (B-operand) straight from global (L2-resident)
  short8 aq[2][2];
  #pragma unroll
  for (int mb = 0; mb < 2; mb++)
    #pragma unroll
    for (int kf = 0; kf < 2; kf++)
      aq[mb][kf] = *(const short8*)(Qg + (size_t)(wave * 32 + mb * 16 + l15) * 64 + kf * 32 + quad * 8);

  // stage tile kt's K/V' into buffer buf (async DMA, pre-swizzled source)
  auto stage = [&](int kt, int buf) {
    const unsigned short* Kt = Kg + (size_t)kt * 64 * DK_;
    unsigned short* Kd = &Ks[buf * 4096];
    unsigned short* Vd = &Vs[buf * (VROWS * 64)];
    #pragma unroll
    for (int i = 0; i < 2; i++) {
      int p = i * 256 + t;
      int rk = p >> 3, ck = (p & 7) ^ (rk & 7);
      ld_lds16(Kt + (size_t)rk * DK_ + ck * 8, &Kd[(i * 256 + wslot) * 8]);
      ld_lds16(Vg + (size_t)rk * S_ + kt * 64 + ck * 8, &Vd[(i * 256 + wslot) * 8]);
    }
    if (wave == (kt & 3))
      Vd[64 * 64 + lane] = (mv[kt >> 2] != 0) ? (unsigned short)0x3F80 : (unsigned short)0;
  };

  f32x4 o_acc[2][5] = {};   // [mb][n]; n==4 is the l column (col 0 valid)

  stage(0, 0);
  __syncthreads();          // tile 0 resident

  #pragma unroll 2
  for (int kt = 0; kt < 16; kt++) {
    const int cur = kt & 1;
    if (kt < 15) stage(kt + 1, cur ^ 1);   // in flight across the compute below
    const unsigned short* Kc = &Ks[cur * 4096];
    const unsigned short* Vc = &Vs[cur * (VROWS * 64)];

    // S^T = K·Q^T : lane l15 = q, quad*4+r = key (within 16-tile)
    f32x4 sc[2][4];
    #pragma unroll
    for (int n = 0; n < 4; n++) {
      short8 bk0 = *(const short8*)&Kc[(n * 16 + l15) * 64 + (quad ^ l7) * 8];
      short8 bk1 = *(const short8*)&Kc[(n * 16 + l15) * 64 + ((4 + quad) ^ l7) * 8];
      #pragma unroll
      for (int mb = 0; mb < 2; mb++) {
        f32x4 c = {};
        c = __builtin_amdgcn_mfma_f32_16x16x32_bf16(bk0, aq[mb][0], c, 0, 0, 0);
        c = __builtin_amdgcn_mfma_f32_16x16x32_bf16(bk1, aq[mb][1], c, 0, 0, 0);
        sc[mb][n] = c;
      }
    }
    // exp2 (raw v_exp_f32) + packed b64 P write: P[q][key]
    #pragma unroll
    for (int mb = 0; mb < 2; mb++)
      #pragma unroll
      for (int n = 0; n < 4; n++) {
        ushort4 pk;
        pk.x = f2bf_trunc(__builtin_amdgcn_exp2f(sc[mb][n][0]));
        pk.y = f2bf_trunc(__builtin_amdgcn_exp2f(sc[mb][n][1]));
        pk.z = f2bf_trunc(__builtin_amdgcn_exp2f(sc[mb][n][2]));
        pk.w = f2bf_trunc(__builtin_amdgcn_exp2f(sc[mb][n][3]));
        *(ushort4*)&Pl[(wave * 32 + mb * 16 + l15) * PLD + n * 16 + quad * 4] = pk;
      }
    // PV (+l): O[q][d] += P[q][key]·V'[key][d]; n=4 reads mask row -> l in col 0
    #pragma unroll
    for (int kf = 0; kf < 2; kf++) {
      short8 ap[2];
      #pragma unroll
      for (int mb = 0; mb < 2; mb++)
        ap[mb] = *(const short8*)&Pl[(wave * 32 + mb * 16 + l15) * PLD + kf * 32 + quad * 8];
      #pragma unroll
      for (int n = 0; n < 5; n++) {
        short8 bv = *(const short8*)&Vc[(n * 16 + l15) * 64 + ((kf * 4 + quad) ^ l7) * 8];
        #pragma unroll
        for (int mb = 0; mb < 2; mb++)
          o_acc[mb][n] = __builtin_amdgcn_mfma_f32_16x16x32_bf16(ap[mb], bv, o_acc[mb][n], 0, 0, 0);
      }
    }
    __syncthreads();   // drains this iter's stage loads (issued ~1000cy ago)
  }

  // epilogue: l lives in o_acc[mb][4][r] at l15==0 -> broadcast within quad
  #pragma unroll
  for (int mb = 0; mb < 2; mb++)
    #pragma unroll
    for (int r = 0; r < 4; r++) {
      float l = __shfl(o_acc[mb][4][r], lane & 48, 64);
      float inv = __builtin_amdgcn_rcpf(l);
      int qrow = qt * 128 + wave * 32 + mb * 16 + quad * 4 + r;
      #pragma unroll
      for (int n = 0; n < 4; n++) {
        int col = h * 64 + n * 16 + l15;
        O[((size_t)b * S_ + qrow) * D_ + col] = f2bf(o_acc[mb][n][r] * inv);
      }
    }
}

extern "C" void kernel_launch(void* const* d_in, const int* in_sizes, int n_in,
                              void* d_out, int out_size, void* d_ws, size_t ws_size,
                              hipStream_t stream) {
  (void)in_sizes; (void)n_in; (void)out_size; (void)ws_size;
  const float* x  = (const float*)d_in[0];
  const int* masks = (const int*)d_in[1];
  const float* Wq = (const float*)d_in[2];
  const float* bq = (const float*)d_in[3];
  const float* Wk = (const float*)d_in[4];
  const float* bk = (const float*)d_in[5];
  const float* Wv = (const float*)d_in[6];
  const float* bv = (const float*)d_in[7];
  const float* Wo = (const float*)d_in[8];
  const float* bo = (const float*)d_in[9];

  char* p = (char*)d_ws;
  unsigned short* xb    = (unsigned short*)p; p += (size_t)8192 * 1024 * 2;
  unsigned short* WqkvT = (unsigned short*)p; p += (size_t)3072 * 1024 * 2;
  unsigned short* WoT   = (unsigned short*)p; p += (size_t)1024 * 1024 * 2;
  unsigned short* q     = (unsigned short*)p; p += (size_t)8192 * 1024 * 2;
  unsigned short* kk    = (unsigned short*)p; p += (size_t)8192 * 1024 * 2;
  unsigned short* vT    = (unsigned short*)p; p += (size_t)8192 * 1024 * 2;
  unsigned short* at    = (unsigned short*)p; p += (size_t)8192 * 1024 * 2;

  prep_kernel<<<dim3(16, 16, 36), 256, 0, stream>>>(
      x, xb, Wq, Wk, Wv, Wo,
      WqkvT, WqkvT + (size_t)1024 * 1024, WqkvT + (size_t)2048 * 1024, WoT);
  gemm_qkv<<<dim3(24, 64), 256, 0, stream>>>(xb, WqkvT, bq, bk, bv, masks, q, kk, vT);
  attn_kernel<<<dim3(128, 8), 256, 0, stream>>>(q, kk, vT, masks, at);
  gemm_out<<<dim3(8, 64), 256, 0, stream>>>(at, WoT, bo, (float*)d_out);
}

// Round 3
// 239.280 us; speedup vs baseline: 1.0433x; 1.0089x over previous
//
#include <hip/hip_runtime.h>
#include <stdint.h>

#define B_ 8
#define S_ 1024
#define D_ 1024
#define H_ 16
#define DK_ 64
#define DV_ 64

typedef __attribute__((ext_vector_type(8))) short short8;
typedef __attribute__((ext_vector_type(4))) float f32x4;

__device__ __forceinline__ unsigned short f2bf(float f) {
  union { float f; unsigned u; } v; v.f = f;
  return (unsigned short)((v.u + 0x7fffu + ((v.u >> 16) & 1u)) >> 16);
}
__device__ __forceinline__ unsigned short f2bf_trunc(float f) {
  union { float f; unsigned u; } v; v.f = f;
  return (unsigned short)(v.u >> 16);
}

// async global->LDS, 16B per lane; LDS dest = wave-uniform base + lane*16
__device__ __forceinline__ void ld_lds16(const unsigned short* g, unsigned short* l) {
  __builtin_amdgcn_global_load_lds((const __attribute__((address_space(1))) void*)g,
                                   (__attribute__((address_space(3))) void*)l, 16, 0, 0);
}

// -------- fused prep: x fp32->bf16 (z>=4) + 4 weight transposes (z<4) --------
__global__ __launch_bounds__(256) void prep_kernel(const float* __restrict__ x,
                                                   unsigned short* __restrict__ xb,
                                                   const float* __restrict__ W0,
                                                   const float* __restrict__ W1,
                                                   const float* __restrict__ W2,
                                                   const float* __restrict__ W3,
                                                   unsigned short* __restrict__ T0,
                                                   unsigned short* __restrict__ T1,
                                                   unsigned short* __restrict__ T2,
                                                   unsigned short* __restrict__ T3) {
  const int z = blockIdx.z;
  if (z >= 4) {
    size_t blk = (size_t)(z - 4) * 256 + blockIdx.y * 16 + blockIdx.x;
    size_t i = (blk * 256 + threadIdx.x) * 4;
    float4 v = *(const float4*)(x + i);
    ushort4 o;
    o.x = f2bf(v.x); o.y = f2bf(v.y); o.z = f2bf(v.z); o.w = f2bf(v.w);
    *(ushort4*)(xb + i) = o;
    return;
  }
  __shared__ __align__(16) unsigned short tl[64][65];
  const float* W; unsigned short* Wt;
  switch (z) {
    case 0: W = W0; Wt = T0; break;
    case 1: W = W1; Wt = T1; break;
    case 2: W = W2; Wt = T2; break;
    default: W = W3; Wt = T3; break;
  }
  const int xx = threadIdx.x & 63;
  const int y4 = threadIdx.x >> 6;
  const int bn = blockIdx.x * 64;   // N base
  const int bk = blockIdx.y * 64;   // K base
  #pragma unroll
  for (int r = y4; r < 64; r += 4)
    tl[r][xx] = f2bf(W[(size_t)(bk + r) * 1024 + bn + xx]);
  __syncthreads();
  #pragma unroll
  for (int r = y4; r < 64; r += 4)
    Wt[(size_t)(bn + r) * 1024 + bk + xx] = tl[xx][r];
}

// ==================== 8-phase pipelined GEMM (m201-template port) ====================
// Tile 256(M) x 128(N), BK=64, 512 threads = 8 waves (4M x 2N), per-wave 64x64.
// LDS: A dbuf 2 x [256][64], B dbuf 2 x [128][64] (XOR-swizzled col-blocks) = 96 KiB.
// Per K-tile: 4 phases {ds_read subtile; issue 1 half-tile gload_lds; barrier;
// lgkmcnt(0); setprio(1); 8 MFMA; setprio(0); barrier}; vmcnt(2) once per K-tile
// (never 0 in main loop). Staging cadence (K-tile J): p0/p1 stage A(J+1) halves
// (A slot J+1 freed at end of C(J-1)); p2 stages B(J+2) (B slot J freed after p1,
// certified by p1's per-wave lgkmcnt(0) + p1's ending barrier).

struct SJob { const unsigned short* g; unsigned short* l; };

// stage 128 rows x 64 cols (bf16) from G (row stride 1024) into L, linear dest,
// pre-swizzled source column blocks (cb ^ (r&7)).
__device__ __forceinline__ void stage128(const unsigned short* __restrict__ G,
                                         unsigned short* __restrict__ L, int t) {
  #pragma unroll
  for (int i = 0; i < 2; i++) {
    int s = i * 512 + t;
    int r = s >> 3, cb = s & 7;
    int c = cb ^ (r & 7);
    ld_lds16(G + (size_t)r * 1024 + c * 8, L + (size_t)s * 8);
  }
}

template <bool SW>
__device__ __forceinline__ f32x4 MM(short8 a, short8 b, f32x4 c) {
  if constexpr (SW) return __builtin_amdgcn_mfma_f32_16x16x32_bf16(b, a, c, 0, 0, 0);
  else              return __builtin_amdgcn_mfma_f32_16x16x32_bf16(a, b, c, 0, 0, 0);
}

template <bool SW, int VM>
__device__ __forceinline__ void ktile(const unsigned short* __restrict__ As_,
                                      const unsigned short* __restrict__ Bs_,
                                      f32x4 (&acc)[4][4],
                                      SJob s0, SJob s1, SJob s2,
                                      int t, int wm, int wn, int l15, int quad, int l7) {
  const int cb0 = (quad ^ l7) * 8;         // kf0 col block (swizzled)
  const int cb1 = ((4 | quad) ^ l7) * 8;   // kf1 col block
  short8 b0[4], b1[4];

  // ---------- phase 0: mi{0,1} x kf0 ----------
  short8 a0k0 = *(const short8*)&As_[(wm + 0 * 16 + l15) * 64 + cb0];
  short8 a1k0 = *(const short8*)&As_[(wm + 1 * 16 + l15) * 64 + cb0];
  #pragma unroll
  for (int ni = 0; ni < 4; ni++)
    b0[ni] = *(const short8*)&Bs_[(wn + ni * 16 + l15) * 64 + cb0];
  if (s0.g) stage128(s0.g, s0.l, t);
  __builtin_amdgcn_s_barrier();
  asm volatile("s_waitcnt lgkmcnt(0)" ::: "memory");
  __builtin_amdgcn_s_setprio(1);
  #pragma unroll
  for (int ni = 0; ni < 4; ni++) {
    acc[0][ni] = MM<SW>(a0k0, b0[ni], acc[0][ni]);
    acc[1][ni] = MM<SW>(a1k0, b0[ni], acc[1][ni]);
  }
  __builtin_amdgcn_s_setprio(0);
  __builtin_amdgcn_s_barrier();

  // ---------- phase 1: mi{0,1} x kf1 ----------
  short8 a0k1 = *(const short8*)&As_[(wm + 0 * 16 + l15) * 64 + cb1];
  short8 a1k1 = *(const short8*)&As_[(wm + 1 * 16 + l15) * 64 + cb1];
  #pragma unroll
  for (int ni = 0; ni < 4; ni++)
    b1[ni] = *(const short8*)&Bs_[(wn + ni * 16 + l15) * 64 + cb1];
  if (s1.g) stage128(s1.g, s1.l, t);
  __builtin_amdgcn_s_barrier();
  asm volatile("s_waitcnt lgkmcnt(0)" ::: "memory");
  __builtin_amdgcn_s_setprio(1);
  #pragma unroll
  for (int ni = 0; ni < 4; ni++) {
    acc[0][ni] = MM<SW>(a0k1, b1[ni], acc[0][ni]);
    acc[1][ni] = MM<SW>(a1k1, b1[ni], acc[1][ni]);
  }
  __builtin_amdgcn_s_setprio(0);
  __builtin_amdgcn_s_barrier();

  // ---------- phase 2: mi{2,3} x kf0 ----------
  short8 a2k0 = *(const short8*)&As_[(wm + 2 * 16 + l15) * 64 + cb0];
  short8 a3k0 = *(const short8*)&As_[(wm + 3 * 16 + l15) * 64 + cb0];
  if (s2.g) stage128(s2.g, s2.l, t);
  __builtin_amdgcn_s_barrier();
  asm volatile("s_waitcnt lgkmcnt(0)" ::: "memory");
  __builtin_amdgcn_s_setprio(1);
  #pragma unroll
  for (int ni = 0; ni < 4; ni++) {
    acc[2][ni] = MM<SW>(a2k0, b0[ni], acc[2][ni]);
    acc[3][ni] = MM<SW>(a3k0, b0[ni], acc[3][ni]);
  }
  __builtin_amdgcn_s_setprio(0);
  __builtin_amdgcn_s_barrier();

  // ---------- phase 3: mi{2,3} x kf1 ----------
  short8 a2k1 = *(const short8*)&As_[(wm + 2 * 16 + l15) * 64 + cb1];
  short8 a3k1 = *(const short8*)&As_[(wm + 3 * 16 + l15) * 64 + cb1];
  __builtin_amdgcn_s_barrier();
  asm volatile("s_waitcnt lgkmcnt(0)" ::: "memory");
  __builtin_amdgcn_s_setprio(1);
  #pragma unroll
  for (int ni = 0; ni < 4; ni++) {
    acc[2][ni] = MM<SW>(a2k1, b1[ni], acc[2][ni]);
    acc[3][ni] = MM<SW>(a3k1, b1[ni], acc[3][ni]);
  }
  __builtin_amdgcn_s_setprio(0);
  if constexpr (VM == 2) asm volatile("s_waitcnt vmcnt(2)" ::: "memory");
  else                   asm volatile("s_waitcnt vmcnt(0)" ::: "memory");
  __builtin_amdgcn_s_barrier();
}

template <bool SW>
__device__ __forceinline__ void gemm_core(const unsigned short* __restrict__ Ag,
                                          const unsigned short* __restrict__ Bg,
                                          unsigned short* __restrict__ Asl,
                                          unsigned short* __restrict__ Bsl,
                                          f32x4 (&acc)[4][4],
                                          int t, int wm, int wn, int l15, int quad, int l7) {
  // prologue: A(0) both halves -> slot0, B(0) -> slot0, B(1) -> slot1
  stage128(Ag, &Asl[0], t);
  stage128(Ag + 128 * 1024, &Asl[8192], t);
  stage128(Bg, &Bsl[0], t);
  stage128(Bg + 64, &Bsl[8192], t);
  asm volatile("s_waitcnt vmcnt(2)" ::: "memory");   // A(0),B(0) landed; B(1) in flight
  __builtin_amdgcn_s_barrier();

  #pragma unroll 1
  for (int tt = 0; tt < 7; tt++) {
    const int J0 = 2 * tt;
    // K-tile J0 (slot 0): stage A(J0+1)->slot1, B(J0+2)->slot0
    ktile<SW, 2>(&Asl[0], &Bsl[0], acc,
                 SJob{Ag + (size_t)(J0 + 1) * 64,              &Asl[16384]},
                 SJob{Ag + (size_t)(J0 + 1) * 64 + 128 * 1024, &Asl[16384 + 8192]},
                 SJob{Bg + (size_t)(J0 + 2) * 64,              &Bsl[0]},
                 t, wm, wn, l15, quad, l7);
    // K-tile J0+1 (slot 1): stage A(J0+2)->slot0, B(J0+3)->slot1
    ktile<SW, 2>(&Asl[16384], &Bsl[8192], acc,
                 SJob{Ag + (size_t)(J0 + 2) * 64,              &Asl[0]},
                 SJob{Ag + (size_t)(J0 + 2) * 64 + 128 * 1024, &Asl[8192]},
                 SJob{Bg + (size_t)(J0 + 3) * 64,              &Bsl[8192]},
                 t, wm, wn, l15, quad, l7);
  }
  // K-tile 14 (slot 0): stage A(15) only; full drain before C(15)
  ktile<SW, 0>(&Asl[0], &Bsl[0], acc,
               SJob{Ag + (size_t)15 * 64,              &Asl[16384]},
               SJob{Ag + (size_t)15 * 64 + 128 * 1024, &Asl[16384 + 8192]},
               SJob{nullptr, nullptr},
               t, wm, wn, l15, quad, l7);
  // K-tile 15 (slot 1): no staging
  ktile<SW, 0>(&Asl[16384], &Bsl[8192], acc,
               SJob{nullptr, nullptr}, SJob{nullptr, nullptr}, SJob{nullptr, nullptr},
               t, wm, wn, l15, quad, l7);
}

// ------------- fused QKV GEMM: A (8192x1024), Bt (3072x1024) -------------
// blockIdx.x 0..7 -> q (scaled), 8..15 -> k, 16..23 -> v (transposed, mask folded)
__global__ __launch_bounds__(512, 2) void gemm_qkv8(const unsigned short* __restrict__ A,
                                                    const unsigned short* __restrict__ Bt,
                                                    const float* __restrict__ bq,
                                                    const float* __restrict__ bk,
                                                    const float* __restrict__ bv,
                                                    const int* __restrict__ masks,
                                                    unsigned short* __restrict__ q,
                                                    unsigned short* __restrict__ kk,
                                                    unsigned short* __restrict__ vT) {
  extern __shared__ unsigned short lds[];
  unsigned short* Asl = lds;               // 2 x 256x64
  unsigned short* Bsl = lds + 2 * 16384;   // 2 x 128x64
  const int t = threadIdx.x;
  const int w = t >> 6, lane = t & 63;
  const int l15 = lane & 15, quad = lane >> 4, l7 = l15 & 7;
  const int bm = blockIdx.y * 256, bn = blockIdx.x * 128;
  const int wm = (w >> 1) * 64, wn = (w & 1) * 64;
  const bool vsec = (blockIdx.x >= 16);
  const unsigned short* Ag = A + (size_t)bm * 1024;
  const unsigned short* Bg = Bt + (size_t)bn * 1024;

  f32x4 acc[4][4] = {};
  if (!vsec) gemm_core<false>(Ag, Bg, Asl, Bsl, acc, t, wm, wn, l15, quad, l7);
  else       gemm_core<true >(Ag, Bg, Asl, Bsl, acc, t, wm, wn, l15, quad, l7);

  if (!vsec) {
    int sec = blockIdx.x >> 3;   // 0 -> q, 1 -> k
    const float* bsel = (sec == 0) ? bq : bk;
    unsigned short* dst = (sec == 0) ? q : kk;
    float scale = (sec == 0) ? 0.180336880f : 1.0f;  // 0.125*log2(e) folded into q
    #pragma unroll
    for (int ni = 0; ni < 4; ni++) {
      int c = (bn & 1023) + wn + ni * 16 + l15;
      float bvv = bsel[c];
      int hh = c >> 6, d = c & 63;
      #pragma unroll
      for (int mi = 0; mi < 4; mi++) {
        int row0 = bm + wm + mi * 16 + quad * 4;
        #pragma unroll
        for (int r = 0; r < 4; r++) {
          int row = row0 + r;
          int b = row >> 10, s = row & 1023;
          dst[(((size_t)(b * H_ + hh)) * S_ + s) * DK_ + d] = f2bf((acc[mi][ni][r] + bvv) * scale);
        }
      }
    }
  } else {
    // transposed accum: lane l15 -> row (s), quad*4+r -> col (d); mask folded
    #pragma unroll
    for (int ni = 0; ni < 4; ni++) {
      int cbase = (bn & 1023) + wn + ni * 16;
      #pragma unroll
      for (int mi = 0; mi < 4; mi++) {
        int row = bm + wm + mi * 16 + l15;
        int b = row >> 10, s = row & 1023;
        float mf = (masks[b * S_ + s] != 0) ? 1.0f : 0.0f;
        #pragma unroll
        for (int r = 0; r < 4; r++) {
          int c = cbase + quad * 4 + r;
          int hh = c >> 6, d = c & 63;
          vT[(((size_t)(b * H_ + hh)) * DV_ + d) * S_ + s] = f2bf((acc[mi][ni][r] + bv[c]) * mf);
        }
      }
    }
  }
}

// ------- out GEMM: A (8192x1024) bf16, Bt (1024x1024) -> fp32, 256 blocks -------
__global__ __launch_bounds__(512, 2) void gemm_out8(const unsigned short* __restrict__ A,
                                                    const unsigned short* __restrict__ Bt,
                                                    const float* __restrict__ bias,
                                                    float* __restrict__ Cout) {
  extern __shared__ unsigned short lds[];
  unsigned short* Asl = lds;
  unsigned short* Bsl = lds + 2 * 16384;
  const int t = threadIdx.x;
  const int w = t >> 6, lane = t & 63;
  const int l15 = lane & 15, quad = lane >> 4, l7 = l15 & 7;
  const int bm = blockIdx.y * 256, bn = blockIdx.x * 128;
  const int wm = (w >> 1) * 64, wn = (w & 1) * 64;
  const unsigned short* Ag = A + (size_t)bm * 1024;
  const unsigned short* Bg = Bt + (size_t)bn * 1024;

  f32x4 acc[4][4] = {};
  gemm_core<false>(Ag, Bg, Asl, Bsl, acc, t, wm, wn, l15, quad, l7);

  #pragma unroll
  for (int ni = 0; ni < 4; ni++) {
    int col = bn + wn + ni * 16 + l15;
    float bvv = bias[col];
    #pragma unroll
    for (int mi = 0; mi < 4; mi++) {
      int row0 = bm + wm + mi * 16 + quad * 4;
      #pragma unroll
      for (int r = 0; r < 4; r++)
        Cout[(size_t)(row0 + r) * 1024 + col] = acc[mi][ni][r] + bvv;
    }
  }
}

// ------------------------- flash attention v3 (unchanged from r2) -------------------------
#define PLD 72
#define VROWS 65   // per-buffer V rows: 64 V' + 1 mask row
__global__ __launch_bounds__(256) void attn_kernel(const unsigned short* __restrict__ Q,
                                                   const unsigned short* __restrict__ Kb,
                                                   const unsigned short* __restrict__ Vt,
                                                   const int* __restrict__ masks,
                                                   unsigned short* __restrict__ O) {
  __shared__ __align__(16) unsigned short Pl[128 * PLD];            // P tiles (stride 72)
  __shared__ __align__(16) unsigned short Ks[2 * 64 * 64];          // K dbuf
  __shared__ __align__(16) unsigned short Vs[(2 * VROWS + 15) * 64];// V' dbuf + mask rows
  const int t = threadIdx.x;
  const int wave = t >> 6, lane = t & 63;
  const int l15 = lane & 15, quad = lane >> 4;
  const int l7 = l15 & 7;
  const int bh = blockIdx.x;       // 0..127  (XCD-locality key)
  const int qt = blockIdx.y;       // 0..7
  const int b = bh >> 4, h = bh & 15;

  const unsigned short* Qg = Q + ((size_t)bh * S_ + qt * 128) * DK_;
  const unsigned short* Kg = Kb + (size_t)bh * S_ * DK_;
  const unsigned short* Vg = Vt + (size_t)bh * DV_ * S_;
  const int wslot = (t & ~63);

  int mv[4];
  #pragma unroll
  for (int j = 0; j < 4; j++)
    mv[j] = masks[b * S_ + (j * 4 + wave) * 64 + lane];

  // Q fragments (B-operand) straight from global (L2-resident)
  short8 aq[2][2];
  #pragma unroll
  for (int mb = 0; mb < 2; mb++)
    #pragma unroll
    for (int kf = 0; kf < 2; kf++)
      aq[mb][kf] = *(const short8*)(Qg + (size_t)(wave * 32 + mb * 16 + l15) * 64 + kf * 32 + quad * 8);

  auto stage = [&](int kt, int buf) {
    const unsigned short* Kt = Kg + (size_t)kt * 64 * DK_;
    unsigned short* Kd = &Ks[buf * 4096];
    unsigned short* Vd = &Vs[buf * (VROWS * 64)];
    #pragma unroll
    for (int i = 0; i < 2; i++) {
      int p = i * 256 + t;
      int rk = p >> 3, ck = (p & 7) ^ (rk & 7);
      ld_lds16(Kt + (size_t)rk * DK_ + ck * 8, &Kd[(i * 256 + wslot) * 8]);
      ld_lds16(Vg + (size_t)rk * S_ + kt * 64 + ck * 8, &Vd[(i * 256 + wslot) * 8]);
    }
    if (wave == (kt & 3))
      Vd[64 * 64 + lane] = (mv[kt >> 2] != 0) ? (unsigned short)0x3F80 : (unsigned short)0;
  };

  f32x4 o_acc[2][5] = {};   // [mb][n]; n==4 is the l column (col 0 valid)

  stage(0, 0);
  __syncthreads();          // tile 0 resident

  #pragma unroll 2
  for (int kt = 0; kt < 16; kt++) {
    const int cur = kt & 1;
    if (kt < 15) stage(kt + 1, cur ^ 1);   // in flight across the compute below
    const unsigned short* Kc = &Ks[cur * 4096];
    const unsigned short* Vc = &Vs[cur * (VROWS * 64)];

    // S^T = K·Q^T : lane l15 = q, quad*4+r = key (within 16-tile)
    f32x4 sc[2][4];
    #pragma unroll
    for (int n = 0; n < 4; n++) {
      short8 bk0 = *(const short8*)&Kc[(n * 16 + l15) * 64 + (quad ^ l7) * 8];
      short8 bk1 = *(const short8*)&Kc[(n * 16 + l15) * 64 + ((4 + quad) ^ l7) * 8];
      #pragma unroll
      for (int mb = 0; mb < 2; mb++) {
        f32x4 c = {};
        c = __builtin_amdgcn_mfma_f32_16x16x32_bf16(bk0, aq[mb][0], c, 0, 0, 0);
        c = __builtin_amdgcn_mfma_f32_16x16x32_bf16(bk1, aq[mb][1], c, 0, 0, 0);
        sc[mb][n] = c;
      }
    }
    // exp2 (raw v_exp_f32) + packed b64 P write: P[q][key]
    #pragma unroll
    for (int mb = 0; mb < 2; mb++)
      #pragma unroll
      for (int n = 0; n < 4; n++) {
        ushort4 pk;
        pk.x = f2bf_trunc(__builtin_amdgcn_exp2f(sc[mb][n][0]));
        pk.y = f2bf_trunc(__builtin_amdgcn_exp2f(sc[mb][n][1]));
        pk.z = f2bf_trunc(__builtin_amdgcn_exp2f(sc[mb][n][2]));
        pk.w = f2bf_trunc(__builtin_amdgcn_exp2f(sc[mb][n][3]));
        *(ushort4*)&Pl[(wave * 32 + mb * 16 + l15) * PLD + n * 16 + quad * 4] = pk;
      }
    // PV (+l): O[q][d] += P[q][key]·V'[key][d]; n=4 reads mask row -> l in col 0
    #pragma unroll
    for (int kf = 0; kf < 2; kf++) {
      short8 ap[2];
      #pragma unroll
      for (int mb = 0; mb < 2; mb++)
        ap[mb] = *(const short8*)&Pl[(wave * 32 + mb * 16 + l15) * PLD + kf * 32 + quad * 8];
      #pragma unroll
      for (int n = 0; n < 5; n++) {
        short8 bv = *(const short8*)&Vc[(n * 16 + l15) * 64 + ((kf * 4 + quad) ^ l7) * 8];
        #pragma unroll
        for (int mb = 0; mb < 2; mb++)
          o_acc[mb][n] = __builtin_amdgcn_mfma_f32_16x16x32_bf16(ap[mb], bv, o_acc[mb][n], 0, 0, 0);
      }
    }
    __syncthreads();   // drains this iter's stage loads (issued ~1000cy ago)
  }

  // epilogue: l lives in o_acc[mb][4][r] at l15==0 -> broadcast within quad
  #pragma unroll
  for (int mb = 0; mb < 2; mb++)
    #pragma unroll
    for (int r = 0; r < 4; r++) {
      float l = __shfl(o_acc[mb][4][r], lane & 48, 64);
      float inv = __builtin_amdgcn_rcpf(l);
      int qrow = qt * 128 + wave * 32 + mb * 16 + quad * 4 + r;
      #pragma unroll
      for (int n = 0; n < 4; n++) {
        int col = h * 64 + n * 16 + l15;
        O[((size_t)b * S_ + qrow) * D_ + col] = f2bf(o_acc[mb][n][r] * inv);
      }
    }
}

extern "C" void kernel_launch(void* const* d_in, const int* in_sizes, int n_in,
                              void* d_out, int out_size, void* d_ws, size_t ws_size,
                              hipStream_t stream) {
  (void)in_sizes; (void)n_in; (void)out_size; (void)ws_size;
  const float* x  = (const float*)d_in[0];
  const int* masks = (const int*)d_in[1];
  const float* Wq = (const float*)d_in[2];
  const float* bq = (const float*)d_in[3];
  const float* Wk = (const float*)d_in[4];
  const float* bk = (const float*)d_in[5];
  const float* Wv = (const float*)d_in[6];
  const float* bv = (const float*)d_in[7];
  const float* Wo = (const float*)d_in[8];
  const float* bo = (const float*)d_in[9];

  char* p = (char*)d_ws;
  unsigned short* xb    = (unsigned short*)p; p += (size_t)8192 * 1024 * 2;
  unsigned short* WqkvT = (unsigned short*)p; p += (size_t)3072 * 1024 * 2;
  unsigned short* WoT   = (unsigned short*)p; p += (size_t)1024 * 1024 * 2;
  unsigned short* q     = (unsigned short*)p; p += (size_t)8192 * 1024 * 2;
  unsigned short* kk    = (unsigned short*)p; p += (size_t)8192 * 1024 * 2;
  unsigned short* vT    = (unsigned short*)p; p += (size_t)8192 * 1024 * 2;
  unsigned short* at    = (unsigned short*)p; p += (size_t)8192 * 1024 * 2;

  static bool attr_done = false;
  if (!attr_done) {
    hipFuncSetAttribute((const void*)gemm_qkv8, hipFuncAttributeMaxDynamicSharedMemorySize, 98304);
    hipFuncSetAttribute((const void*)gemm_out8, hipFuncAttributeMaxDynamicSharedMemorySize, 98304);
    attr_done = true;
  }

  prep_kernel<<<dim3(16, 16, 36), 256, 0, stream>>>(
      x, xb, Wq, Wk, Wv, Wo,
      WqkvT, WqkvT + (size_t)1024 * 1024, WqkvT + (size_t)2048 * 1024, WoT);
  gemm_qkv8<<<dim3(24, 32), 512, 98304, stream>>>(xb, WqkvT, bq, bk, bv, masks, q, kk, vT);
  attn_kernel<<<dim3(128, 8), 256, 0, stream>>>(q, kk, vT, masks, at);
  gemm_out8<<<dim3(8, 32), 512, 98304, stream>>>(at, WoT, bo, (float*)d_out);
}